// Round 1
// baseline (30076.703 us; speedup 1.0000x reference)
//
#include <hip/hip_runtime.h>
#include <hip/hip_cooperative_groups.h>

namespace cg = cooperative_groups;

#define H 1024
#define V 32000
#define STEPS 375
#define NBLK 256          // blocks (1 per CU)
#define NTHR 512          // threads per block (8 waves)
#define WPB (NTHR / 64)   // waves per block = 8
#define RPB (V / NBLK)    // logit rows per block = 125

__device__ __forceinline__ float dot4(const float4 a, const float4 b) {
    return fmaf(a.x, b.x, fmaf(a.y, b.y, fmaf(a.z, b.z, a.w * b.w)));
}

__device__ __forceinline__ float wave_sum(float v) {
#pragma unroll
    for (int off = 32; off > 0; off >>= 1) v += __shfl_xor(v, off);
    return v;
}

__device__ __forceinline__ float wave_max(float v) {
#pragma unroll
    for (int off = 32; off > 0; off >>= 1) v = fmaxf(v, __shfl_xor(v, off));
    return v;
}

// All lanes return argmax over 256 partials (tie -> smallest index).
__device__ __forceinline__ int argmax_tok(const float* pm_p, const int* pa_p, int lane) {
    float m = -3.4e38f;
    int a = 0x7fffffff;
#pragma unroll
    for (int k = 0; k < NBLK / 64; ++k) {
        float km = pm_p[k * 64 + lane];
        int ka = pa_p[k * 64 + lane];
        if (km > m || (km == m && ka < a)) { m = km; a = ka; }
    }
#pragma unroll
    for (int off = 32; off > 0; off >>= 1) {
        float om = __shfl_xor(m, off);
        int oa = __shfl_xor(a, off);
        if (om > m || (om == m && oa < a)) { m = om; a = oa; }
    }
    return a;
}

// All lanes return logZ = M + log(sum) combined from 256 block partials.
__device__ __forceinline__ float finalize_logZ(const float* pm_p, const float* ps_p, int lane) {
    float mt[4], st[4];
#pragma unroll
    for (int k = 0; k < 4; ++k) {
        mt[k] = pm_p[k * 64 + lane];
        st[k] = ps_p[k * 64 + lane];
    }
    float m = fmaxf(fmaxf(mt[0], mt[1]), fmaxf(mt[2], mt[3]));
    m = wave_max(m);
    float se = st[0] * expf(mt[0] - m) + st[1] * expf(mt[1] - m) +
               st[2] * expf(mt[2] - m) + st[3] * expf(mt[3] - m);
    se = wave_sum(se);
    return m + logf(se);
}

__global__ __launch_bounds__(NTHR, 2) void decoder_kernel(
    const float* __restrict__ enc, const float* __restrict__ emb,
    const float* __restrict__ W_ih, const float* __restrict__ W_hh,
    const float* __restrict__ b_ih, const float* __restrict__ b_hh,
    const float* __restrict__ lin_W, const float* __restrict__ lin_b,
    float* __restrict__ out, float* __restrict__ ws) {
    cg::grid_group grid = cg::this_grid();
    const int tid = threadIdx.x;
    const int lane = tid & 63;
    const int wv = tid >> 6;
    const int b = blockIdx.x;

    // workspace layout (floats)
    float* h_buf = ws;                 // [2][H] ping-pong hidden state
    float* pm = ws + 2 * H;            // [2][NBLK] partial max
    float* psum = pm + 2 * NBLK;       // [2][NBLK] partial sumexp
    int* parg = (int*)(psum + 2 * NBLK); // [2][NBLK] partial argmax

    __shared__ float red_m[WPB], red_s[WPB];
    __shared__ int red_a[WPB];

    // init h (every call: ws is not re-poisoned but we must be deterministic)
    if (b == 0)
        for (int i = tid; i < H; i += NTHR) h_buf[i] = enc[i];
    grid.sync();

    for (int s = 0; s < STEPS; ++s) {
        const int par = s & 1;
        const float* h_cur = h_buf + par * H;
        float* h_next = h_buf + (par ^ 1) * H;

        // ---- GRU (waves 0..3: row i = b*4+wv)  ||  finalize prev logp (waves 4..7)
        if (wv < 4) {
            int tok = 0;
            if (s > 0) {
                const int pp = (s - 1) & 1;
                tok = argmax_tok(pm + pp * NBLK, parg + pp * NBLK, lane);
            }
            const int i = b * 4 + wv;
            const float4* x4 = (const float4*)(emb + (size_t)tok * H);
            const float4* h4 = (const float4*)h_cur;
            float4 xr[4], hr[4];
#pragma unroll
            for (int j = 0; j < 4; ++j) {
                xr[j] = x4[j * 64 + lane];
                hr[j] = h4[j * 64 + lane];
            }
            const float4* wir = (const float4*)(W_ih + (size_t)i * H);
            const float4* wiz = (const float4*)(W_ih + ((size_t)i + H) * H);
            const float4* win = (const float4*)(W_ih + ((size_t)i + 2 * H) * H);
            const float4* whr = (const float4*)(W_hh + (size_t)i * H);
            const float4* whz = (const float4*)(W_hh + ((size_t)i + H) * H);
            const float4* whn = (const float4*)(W_hh + ((size_t)i + 2 * H) * H);
            float sir = 0, siz = 0, sin_ = 0, shr = 0, shz = 0, shn = 0;
#pragma unroll
            for (int j = 0; j < 4; ++j) {
                const int idx = j * 64 + lane;
                sir += dot4(wir[idx], xr[j]);
                siz += dot4(wiz[idx], xr[j]);
                sin_ += dot4(win[idx], xr[j]);
                shr += dot4(whr[idx], hr[j]);
                shz += dot4(whz[idx], hr[j]);
                shn += dot4(whn[idx], hr[j]);
            }
            sir = wave_sum(sir); siz = wave_sum(siz); sin_ = wave_sum(sin_);
            shr = wave_sum(shr); shz = wave_sum(shz); shn = wave_sum(shn);
            if (lane == 0) {
                float r = 1.f / (1.f + expf(-(sir + b_ih[i] + shr + b_hh[i])));
                float z = 1.f / (1.f + expf(-(siz + b_ih[i + H] + shz + b_hh[i + H])));
                float n = tanhf(sin_ + b_ih[i + 2 * H] + r * (shn + b_hh[i + 2 * H]));
                h_next[i] = (1.f - z) * n + z * h_cur[i];
            }
        } else if (s > 0) {
            const int pp = (s - 1) & 1;
            const float logZ = finalize_logZ(pm + pp * NBLK, psum + pp * NBLK, lane);
            float* prow = out + (size_t)(s - 1) * V + (size_t)b * RPB;
            const int t2 = tid - 4 * 64;  // 0..255 over waves 4..7
            if (t2 < RPB) prow[t2] -= logZ;
        }
        grid.sync();

        // ---- logits for step s + per-block online softmax partials
        {
            const float4* h4 = (const float4*)h_next;
            float4 hr[4];
#pragma unroll
            for (int j = 0; j < 4; ++j) hr[j] = h4[j * 64 + lane];
            float m = -3.4e38f, ssum = 0.f;
            int arg = 0x7fffffff;
            float* orow = out + (size_t)s * V;
            const int r0 = b * RPB;
            const int rend = r0 + RPB;
            for (int r = r0 + wv; r < rend; r += 4 * WPB) {
                const int r1 = r + WPB, r2 = r + 2 * WPB, r3 = r + 3 * WPB;
                const bool v1 = r1 < rend, v2 = r2 < rend, v3 = r3 < rend;
                const float4* p0 = (const float4*)(lin_W + (size_t)r * H);
                const float4* p1 = (const float4*)(lin_W + (size_t)(v1 ? r1 : r) * H);
                const float4* p2 = (const float4*)(lin_W + (size_t)(v2 ? r2 : r) * H);
                const float4* p3 = (const float4*)(lin_W + (size_t)(v3 ? r3 : r) * H);
                float4 w0[4], w1[4], w2[4], w3[4];
#pragma unroll
                for (int j = 0; j < 4; ++j) {
                    const int idx = j * 64 + lane;
                    w0[j] = p0[idx]; w1[j] = p1[idx];
                    w2[j] = p2[idx]; w3[j] = p3[idx];
                }
                float a0 = 0, a1 = 0, a2 = 0, a3 = 0;
#pragma unroll
                for (int j = 0; j < 4; ++j) {
                    a0 += dot4(w0[j], hr[j]);
                    a1 += dot4(w1[j], hr[j]);
                    a2 += dot4(w2[j], hr[j]);
                    a3 += dot4(w3[j], hr[j]);
                }
                a0 = wave_sum(a0); a1 = wave_sum(a1);
                a2 = wave_sum(a2); a3 = wave_sum(a3);
                a0 += lin_b[r];
                if (lane == 0) orow[r] = a0;
                if (a0 > m) { ssum *= expf(m - a0); m = a0; arg = r; }
                ssum += expf(a0 - m);
                if (v1) {
                    a1 += lin_b[r1];
                    if (lane == 0) orow[r1] = a1;
                    if (a1 > m) { ssum *= expf(m - a1); m = a1; arg = r1; }
                    ssum += expf(a1 - m);
                }
                if (v2) {
                    a2 += lin_b[r2];
                    if (lane == 0) orow[r2] = a2;
                    if (a2 > m) { ssum *= expf(m - a2); m = a2; arg = r2; }
                    ssum += expf(a2 - m);
                }
                if (v3) {
                    a3 += lin_b[r3];
                    if (lane == 0) orow[r3] = a3;
                    if (a3 > m) { ssum *= expf(m - a3); m = a3; arg = r3; }
                    ssum += expf(a3 - m);
                }
            }
            if (lane == 0) { red_m[wv] = m; red_s[wv] = ssum; red_a[wv] = arg; }
            __syncthreads();
            if (tid == 0) {
                float M = -3.4e38f, S = 0.f;
                int A = 0x7fffffff;
#pragma unroll
                for (int w = 0; w < WPB; ++w) {
                    float mw = red_m[w], sw = red_s[w];
                    int aw = red_a[w];
                    if (mw > M || (mw == M && aw < A)) {
                        S = S * expf(M - mw) + sw; M = mw; A = aw;
                    } else {
                        S += sw * expf(mw - M);
                    }
                }
                pm[par * NBLK + b] = M;
                psum[par * NBLK + b] = S;
                parg[par * NBLK + b] = A;
            }
        }
        grid.sync();
    }

    // ---- finalize last step's logp
    {
        const int pp = (STEPS - 1) & 1;
        const float logZ = finalize_logZ(pm + pp * NBLK, psum + pp * NBLK, lane);
        float* prow = out + (size_t)(STEPS - 1) * V + (size_t)b * RPB;
        if (tid < RPB) prow[tid] -= logZ;
    }
    // ---- final hidden state
    if (b == 0) {
        const float* hf = h_buf + (STEPS & 1) * H;
        for (int i = tid; i < H; i += NTHR) out[(size_t)V * STEPS + i] = hf[i];
    }
}

extern "C" void kernel_launch(void* const* d_in, const int* in_sizes, int n_in,
                              void* d_out, int out_size, void* d_ws, size_t ws_size,
                              hipStream_t stream) {
    const float* enc = (const float*)d_in[0];
    const float* emb = (const float*)d_in[1];
    const float* W_ih = (const float*)d_in[2];
    const float* W_hh = (const float*)d_in[3];
    const float* b_ih = (const float*)d_in[4];
    const float* b_hh = (const float*)d_in[5];
    const float* lin_W = (const float*)d_in[6];
    const float* lin_b = (const float*)d_in[7];
    float* out = (float*)d_out;
    float* ws = (float*)d_ws;

    void* args[] = {&enc, &emb, &W_ih, &W_hh, &b_ih, &b_hh, &lin_W, &lin_b, &out, &ws};
    hipLaunchCooperativeKernel(reinterpret_cast<const void*>(&decoder_kernel),
                               dim3(NBLK), dim3(NTHR), args, 0, stream);
}